// Round 13
// baseline (159.980 us; speedup 1.0000x reference)
//
#include <hip/hip_runtime.h>
#include <hip/hip_bf16.h>

// Problem constants: B=2, S=2048, D=1024, H=16, HD=64, M = B*S = 4096

typedef __attribute__((ext_vector_type(8))) short short8;    // 8 bf16 = 4 VGPR
typedef __attribute__((ext_vector_type(4))) short short4v;   // 4 bf16
typedef __attribute__((ext_vector_type(4))) float f32x4;     // 16x16 C/D frag
typedef __attribute__((ext_vector_type(16))) float f32x16;   // 32x32 C/D frag

static __device__ __forceinline__ short f2bf(float f) {
    union { float f; unsigned u; } c; c.f = f;
    unsigned r = c.u + 0x7fff + ((c.u >> 16) & 1);   // RNE
    return (short)(r >> 16);
}

// packed f32x2 -> bf16x2 (v_cvt_pk_bf16_f32)
static __device__ __forceinline__ unsigned pk_bf16(float a, float b) {
    union { __hip_bfloat162 h; unsigned u; } c;
    c.h = __float22bfloat162_rn(make_float2(a, b));
    return c.u;
}

// async global -> LDS, 16B per lane (global_load_lds_dwordx4).
typedef const void __attribute__((address_space(1)))* gas_ptr;
typedef void __attribute__((address_space(3)))* las_ptr;
static __device__ __forceinline__ void gload16(const void* g, void* l) {
    __builtin_amdgcn_global_load_lds((gas_ptr)g, (las_ptr)l, 16, 0, 0);
}

// ---------------------------------------------------------------------------
// prep: merged f32->bf16 input conversion (3 x 4M elems) + weight transpose
// (4 x W[K][N] f32 -> Wt[N][K] bf16). One dispatch, 10240 blocks.
// ---------------------------------------------------------------------------
__global__ __launch_bounds__(256) void prep(
    const float* __restrict__ X0, const float* __restrict__ X1,
    const float* __restrict__ X2, short* __restrict__ Abf,
    const float* __restrict__ W0, const float* __restrict__ W1,
    const float* __restrict__ W2, const float* __restrict__ W3,
    short* __restrict__ Wt)
{
    __shared__ float tile[32][33];
    const int bid = blockIdx.x;
    if (bid < 6144) {           // --- tobf16: 2048 blocks per input ---
        const int zz = bid >> 11, xb = bid & 2047;
        const float* X = zz == 0 ? X0 : zz == 1 ? X1 : X2;
        short* o = Abf + ((size_t)zz << 22);
        const int i = (xb * 256 + threadIdx.x) * 8;
        const float4 a = *(const float4*)(X + i);
        const float4 b = *(const float4*)(X + i + 4);
        uint4 r;
        r.x = pk_bf16(a.x, a.y); r.y = pk_bf16(a.z, a.w);
        r.z = pk_bf16(b.x, b.y); r.w = pk_bf16(b.z, b.w);
        *(uint4*)(o + i) = r;
    } else {                    // --- wtrans: 1024 blocks per weight ---
        const int wid = bid - 6144;
        const int z = wid >> 10;
        const float* W = z == 0 ? W0 : z == 1 ? W1 : z == 2 ? W2 : W3;
        short* O = Wt + ((size_t)z << 20);
        const int k0 = (wid & 31) * 32, n0 = ((wid >> 5) & 31) * 32;
        const int tx = threadIdx.x & 31, ty = threadIdx.x >> 5;  // (32,8)
        #pragma unroll
        for (int j = 0; j < 32; j += 8)
            tile[ty + j][tx] = W[(k0 + ty + j) * 1024 + n0 + tx];
        __syncthreads();
        #pragma unroll
        for (int j = 0; j < 32; j += 8)
            O[(n0 + ty + j) * 1024 + k0 + tx] = f2bf(tile[tx][ty + j]);
    }
}

// ---------------------------------------------------------------------------
// GEMM core (BM=64, BN=128, BK=32), 4 waves, acc[2][4] of 16x16x32 frags.
// gload16-staged both operands, double-buffered, 1 barrier/K-step.
// gm0/gn0 bound as locals (macro hygiene).
// ---------------------------------------------------------------------------
#define STAGE(buf, k0) do {                                                   \
    gload16(Aa + (size_t)(gm0 + (t >> 2)) * 1024 + (k0) + (t & 3) * 8,        \
            &Al[buf][w * 512]);                                               \
    _Pragma("unroll")                                                         \
    for (int j = 0; j < 2; ++j) {                                             \
        const int c = j * 256 + t;                                            \
        gload16(Ba + (size_t)(gn0 + (c >> 2)) * 1024 + (k0) + (c & 3) * 8,    \
                &Bl[buf][j * 2048 + w * 512]);                                \
    }                                                                         \
} while (0)

#define GEMM_CORE(Aa_, Ba_, m0v, n0v)                                         \
    __shared__ short Al[2][2048];   /* [64 m][32 k] */                        \
    __shared__ short Bl[2][4096];   /* [128 n][32 k] */                       \
    const int t = threadIdx.x;                                                \
    const int gm0 = (m0v), gn0 = (n0v);                                       \
    const int lane = t & 63, w = t >> 6;                                      \
    const int lm = lane & 15, lg = lane >> 4;                                 \
    const int wr = w >> 1, wc = w & 1;                                        \
    f32x4 acc[2][4] = {};                                                     \
    STAGE(0, 0);                                                              \
    __syncthreads();                                                          \
    int buf = 0;                                                              \
    for (int kk = 0; kk < 32; ++kk) {                                         \
        if (kk < 31) STAGE(buf ^ 1, (kk + 1) * 32);                           \
        const short* Ab = Al[buf];                                            \
        const short* Bb = Bl[buf];                                            \
        short8 af[2], bfr[4];                                                 \
        _Pragma("unroll")                                                     \
        for (int mf = 0; mf < 2; ++mf)                                        \
            af[mf] = *(const short8*)(Ab + (wr * 32 + mf * 16 + lm) * 32 + lg * 8); \
        _Pragma("unroll")                                                     \
        for (int nf = 0; nf < 4; ++nf)                                        \
            bfr[nf] = *(const short8*)(Bb + (wc * 64 + nf * 16 + lm) * 32 + lg * 8); \
        _Pragma("unroll")                                                     \
        for (int mf = 0; mf < 2; ++mf)                                        \
            _Pragma("unroll")                                                 \
            for (int nf = 0; nf < 4; ++nf)                                    \
                acc[mf][nf] = __builtin_amdgcn_mfma_f32_16x16x32_bf16(        \
                    af[mf], bfr[nf], acc[mf][nf], 0, 0, 0);                   \
        __syncthreads();                                                      \
        buf ^= 1;                                                             \
    }

// ---------------------------------------------------------------------------
// Merged Q/K/V projection GEMM, bf16 A, T1 XCD-aware bijective swizzle.
// 1536 blocks = 6/CU.
// ---------------------------------------------------------------------------
__global__ __launch_bounds__(256) void gemmqkv(
    const short* __restrict__ Abase, const short* __restrict__ Wt,
    const float* __restrict__ bq, const float* __restrict__ bk,
    const float* __restrict__ bv, short* __restrict__ Qh,
    short* __restrict__ Kh, short* __restrict__ Vt, float qscale)
{
    const int flat = blockIdx.z * 512 + blockIdx.y * 8 + blockIdx.x;
    const int remap = (flat & 7) * 192 + (flat >> 3);   // 1536 % 8 == 0: bijective
    const int z = remap >> 9;
    const int rem = remap & 511;
    const int m0 = (rem >> 3) * 64, n0 = (rem & 7) * 128;

    const short* Aa = Abase + ((size_t)z << 22);
    const short* Ba = Wt + ((size_t)z << 20);
    const float* bias = z == 0 ? bq : z == 1 ? bk : bv;
    short* O = z == 0 ? Qh : z == 1 ? Kh : Vt;
    const float scale = z == 0 ? qscale : 1.0f;

    GEMM_CORE(Aa, Ba, m0, n0)

    // epilogue — D frag: col = lm (n), rows = lg*4 + i (m)
    #pragma unroll
    for (int mf = 0; mf < 2; ++mf) {
        const int mb = m0 + wr * 32 + mf * 16 + lg * 4;
        #pragma unroll
        for (int nf = 0; nf < 4; ++nf) {
            const int n = n0 + wc * 64 + nf * 16 + lm;
            const float bs = bias[n];
            if (z == 2) {   // V^T [B,H,64,S]: 4 consecutive s per lane
                short4v sv;
                #pragma unroll
                for (int i = 0; i < 4; ++i)
                    sv[i] = f2bf(acc[mf][nf][i] + bs);
                const int addr = (((mb >> 11) * 16 + (n >> 6)) * 64 + (n & 63)) * 2048 + (mb & 2047);
                *(short4v*)&O[addr] = sv;
            } else {        // head-split [B,H,S,64]
                #pragma unroll
                for (int i = 0; i < 4; ++i) {
                    const int m = mb + i;
                    const int addr = (((m >> 11) * 16 + (n >> 6)) * 2048 + (m & 2047)) * 64 + (n & 63);
                    O[addr] = f2bf(scale * (acc[mf][nf][i] + bs));
                }
            }
        }
    }
}

// ---------------------------------------------------------------------------
// Final projection: out = Ctx @ Wo^T + bo, f32 flat. 512 blocks, XCD swizzle.
// ---------------------------------------------------------------------------
__global__ __launch_bounds__(256) void gemmo(
    const short* __restrict__ Aa, const short* __restrict__ Ba,
    const float* __restrict__ bias, float* __restrict__ Out)
{
    const int flat = blockIdx.y * 8 + blockIdx.x;
    const int remap = (flat & 7) * 64 + (flat >> 3);    // 512 % 8 == 0: bijective
    const int m0 = (remap >> 3) * 64, n0 = (remap & 7) * 128;

    GEMM_CORE(Aa, Ba, m0, n0)

    #pragma unroll
    for (int mf = 0; mf < 2; ++mf) {
        const int mb = m0 + wr * 32 + mf * 16 + lg * 4;
        #pragma unroll
        for (int nf = 0; nf < 4; ++nf) {
            const int n = n0 + wc * 64 + nf * 16 + lm;
            const float bs = bias[n];
            #pragma unroll
            for (int i = 0; i < 4; ++i)
                Out[(mb + i) * 1024 + n] = acc[mf][nf][i] + bs;
        }
    }
}
#undef STAGE
#undef GEMM_CORE

// ---------------------------------------------------------------------------
// Flash attention v10 — 32x32 MFMA, P via per-wave LDS (layout-error-proof).
// 4 waves x 32 q-rows = 128 q/block; KVBLK=64; grid (16,32).
// Swapped QK^T via mfma_f32_32x32x16_bf16(K,Q): lane owns col q=lane&31.
// C/D (HW-verified m74/m101): row = (reg&3) + 8*(reg>>2) + 4*(lane>>5).
// r12's permlane in-reg P REPLACED: P is written to a per-wave LDS buffer
// [32 q][40 keys] (row = lane's q, keys at reg-mapped offsets 8g+4hi+i) and
// the PV B-frag is read back at k-slot (hi,j) -> key hi*8+j. Since the V
// A-frag uses the SAME k-slot mapping, any error in the assumed A/B k-slot
// layout cancels (P and V agree per-slot on the key) — the only layout
// dependency left is the verified C/D map. Wave-private FIFO LDS ordering
// (proven r3-r8 pattern), no extra barrier.
// Softmax per-lane (exp2 domain) + ONE shfl_xor(32); defer-max (T13);
// K/V [2][64][64] tiles, XOR chunk swizzle both sides, T14 early loads,
// 1 barrier/tile. LDS 43KB; launch_bounds(256,3).
// ---------------------------------------------------------------------------
__global__ __launch_bounds__(256, 3) void attn_k(
    const short* __restrict__ Q, const short* __restrict__ K,
    const short* __restrict__ V, short* __restrict__ Ctx)
{
    __shared__ short Kl[2][64][64];   // [buf][key][d]
    __shared__ short Vl[2][64][64];   // [buf][d][key]
    __shared__ short Pl[4][32][40];   // [wave][q][keys 0..31 of kb-block], pad 8
    const int t = threadIdx.x;
    const int qt = blockIdx.x, bh = blockIdx.y;
    const int lane = t & 63, w = t >> 6;      // 4 waves
    const int lq = lane & 31, hi = lane >> 5;
    const int swc = lq & 7;                   // K/V read chunk swizzle

    // Q fragment (B-operand): col q = lq, k-slot (hi,j) -> k = dc*16 + hi*8 + j
    const int qrow = qt * 128 + w * 32 + lq;
    short8 qf[4];
    #pragma unroll
    for (int dc = 0; dc < 4; ++dc)
        qf[dc] = *(const short8*)(Q + ((size_t)bh * 2048 + qrow) * 64 + dc * 16 + hi * 8);

    float m_run = -3e38f, l_run = 0.f;
    f32x16 o_acc[2] = {};

    // staging: thread t owns K row rk chunks {2ck,2ck+1} and V row rv
    // chunks {2cv,2cv+1} (8-short chunks, 8 per row)
    const int rk = t >> 2, ck = t & 3;
    const short* Kg = K + ((size_t)bh * 2048 + rk) * 64 + ck * 16;
    const short* Vg = V + ((size_t)bh * 64 + rk) * 2048 + ck * 16;
    const int koff0 = rk * 64 + ((ck * 2) ^ (rk & 7)) * 8;
    const int koff1 = rk * 64 + ((ck * 2 + 1) ^ (rk & 7)) * 8;

    {   // prologue: stage tile 0 into buffer 0
        short8 a = *(const short8*)(Kg);
        short8 b = *(const short8*)(Kg + 8);
        short8 c = *(const short8*)(Vg);
        short8 d = *(const short8*)(Vg + 8);
        *(short8*)((short*)Kl[0] + koff0) = a;
        *(short8*)((short*)Kl[0] + koff1) = b;
        *(short8*)((short*)Vl[0] + koff0) = c;
        *(short8*)((short*)Vl[0] + koff1) = d;
    }

    short* prow = &Pl[w][lq][0];
    int cur = 0;

    for (int kt = 0; kt < 32; ++kt) {
        __syncthreads();   // stage[cur] visible; [cur^1] free for writing

        // early-issue global loads for tile kt+1 (T14)
        short8 kn0, kn1, vn0, vn1;
        const bool pfn = (kt < 31);
        if (pfn) {
            const short* Kgn = Kg + (size_t)(kt + 1) * 4096;   // 64 rows * 64
            const short* Vgn = Vg + (kt + 1) * 64;
            kn0 = *(const short8*)(Kgn);
            kn1 = *(const short8*)(Kgn + 8);
            vn0 = *(const short8*)(Vgn);
            vn1 = *(const short8*)(Vgn + 8);
        }

        const short* Kc = (const short*)Kl[cur];
        const short* Vc = (const short*)Vl[cur];

        // ---- S^T = K Q^T : 2 key-blocks x 4 d-chunks of 32x32x16 ----
        f32x16 sacc[2] = {};
        #pragma unroll
        for (int kb = 0; kb < 2; ++kb) {
            const int krow = kb * 32 + lq;
            #pragma unroll
            for (int dc = 0; dc < 4; ++dc) {
                const short8 kf = *(const short8*)(Kc + krow * 64 + ((dc * 2 + hi) ^ swc) * 8);
                sacc[kb] = __builtin_amdgcn_mfma_f32_32x32x16_bf16(kf, qf[dc], sacc[kb], 0, 0, 0);
            }
        }

        // ---- online softmax (exp2 domain), lane owns q = lq ----
        float m8[8];
        #pragma unroll
        for (int kb = 0; kb < 2; ++kb)
            #pragma unroll
            for (int g = 0; g < 4; ++g)
                m8[kb * 4 + g] = fmaxf(fmaxf(sacc[kb][g * 4 + 0], sacc[kb][g * 4 + 1]),
                                       fmaxf(sacc[kb][g * 4 + 2], sacc[kb][g * 4 + 3]));
        float mt = fmaxf(fmaxf(fmaxf(m8[0], m8[1]), fmaxf(m8[2], m8[3])),
                         fmaxf(fmaxf(m8[4], m8[5]), fmaxf(m8[6], m8[7])));
        mt = fmaxf(mt, __shfl_xor(mt, 32));
        if (__any(mt > m_run + 8.0f)) {     // defer-max (T13)
            const float mn = fmaxf(m_run, mt);
            const float alpha = exp2f(m_run - mn);
            l_run *= alpha;
            #pragma unroll
            for (int db = 0; db < 2; ++db)
                #pragma unroll
                for (int r = 0; r < 16; ++r)
                    o_acc[db][r] *= alpha;
            m_run = mn;
        }
        float ps[8];
        #pragma unroll
        for (int kb = 0; kb < 2; ++kb)
            #pragma unroll
            for (int g = 0; g < 4; ++g) {
                float e0 = exp2f(sacc[kb][g * 4 + 0] - m_run);
                float e1 = exp2f(sacc[kb][g * 4 + 1] - m_run);
                float e2 = exp2f(sacc[kb][g * 4 + 2] - m_run);
                float e3 = exp2f(sacc[kb][g * 4 + 3] - m_run);
                sacc[kb][g * 4 + 0] = e0; sacc[kb][g * 4 + 1] = e1;
                sacc[kb][g * 4 + 2] = e2; sacc[kb][g * 4 + 3] = e3;
                ps[kb * 4 + g] = (e0 + e1) + (e2 + e3);
            }
        float rs = ((ps[0] + ps[1]) + (ps[2] + ps[3])) +
                   ((ps[4] + ps[5]) + (ps[6] + ps[7]));
        rs += __shfl_xor(rs, 32);
        l_run += rs;

        // ---- per key-block: P -> per-wave LDS, read PV B-frags, PV ----
        #pragma unroll
        for (int kb = 0; kb < 2; ++kb) {
            // write: reg 4g+i holds key 8g + 4hi + i (C/D map) -> uint2 per g
            #pragma unroll
            for (int g = 0; g < 4; ++g) {
                uint2 pv2;
                pv2.x = pk_bf16(sacc[kb][g * 4 + 0], sacc[kb][g * 4 + 1]);
                pv2.y = pk_bf16(sacc[kb][g * 4 + 2], sacc[kb][g * 4 + 3]);
                *(uint2*)(prow + g * 8 + 4 * hi) = pv2;
            }
            // read B-frags: k-slot (hi,j) -> key c*16 + hi*8 + j
            const short8 pf0 = *(const short8*)(prow + hi * 8);
            const short8 pf1 = *(const short8*)(prow + 16 + hi * 8);

            // late ds_write of tile kt+1 (between the two PV blocks)
            if (kb == 0 && pfn) {
                short* Kn = (short*)Kl[cur ^ 1];
                short* Vn = (short*)Vl[cur ^ 1];
                *(short8*)(Kn + koff0) = kn0;
                *(short8*)(Kn + koff1) = kn1;
                *(short8*)(Vn + koff0) = vn0;
                *(short8*)(Vn + koff1) = vn1;
            }

            #pragma unroll
            for (int db = 0; db < 2; ++db) {
                const int vrow = db * 32 + lq;
                const short8 vf0 = *(const short8*)(Vc + vrow * 64 + ((kb * 4 + 0 + hi) ^ swc) * 8);
                o_acc[db] = __builtin_amdgcn_mfma_f32_32x32x16_bf16(vf0, pf0, o_acc[db], 0, 0, 0);
                const short8 vf1 = *(const short8*)(Vc + vrow * 64 + ((kb * 4 + 2 + hi) ^ swc) * 8);
                o_acc[db] = __builtin_amdgcn_mfma_f32_32x32x16_bf16(vf1, pf1, o_acc[db], 0, 0, 0);
            }
        }
        cur ^= 1;
    }

    // epilogue: ctx[b][q][head*64 + d], d = db*32 + g*8 + 4*hi + i
    const float inv = 1.f / l_run;
    const int b = bh >> 4, hh = bh & 15;
    short* outp = Ctx + ((size_t)b * 2048 + qrow) * 1024 + hh * 64 + 4 * hi;
    #pragma unroll
    for (int db = 0; db < 2; ++db)
        #pragma unroll
        for (int g = 0; g < 4; ++g) {
            uint2 pk2;
            pk2.x = pk_bf16(o_acc[db][g * 4 + 0] * inv, o_acc[db][g * 4 + 1] * inv);
            pk2.y = pk_bf16(o_acc[db][g * 4 + 2] * inv, o_acc[db][g * 4 + 3] * inv);
            *(uint2*)(outp + db * 32 + g * 8) = pk2;
        }
}

// ---------------------------------------------------------------------------
extern "C" void kernel_launch(void* const* d_in, const int* in_sizes, int n_in,
                              void* d_out, int out_size, void* d_ws, size_t ws_size,
                              hipStream_t stream)
{
    const float* query  = (const float*)d_in[0];
    const float* key_in = (const float*)d_in[1];
    const float* value  = (const float*)d_in[2];
    const float* Wq = (const float*)d_in[3];
    const float* bq = (const float*)d_in[4];
    const float* Wk = (const float*)d_in[5];
    const float* bk = (const float*)d_in[6];
    const float* Wv = (const float*)d_in[7];
    const float* bv = (const float*)d_in[8];
    const float* Wo = (const float*)d_in[9];
    const float* bo = (const float*)d_in[10];
    float* out = (float*)d_out;

    char* ws = (char*)d_ws;
    short* Wt  = (short*)(ws);               // 4 x 2MB transposed bf16 weights
    short* Abf = (short*)(ws + (8  << 20));  // 3 x 8MB bf16 inputs (q,k,v)
    short* Qh  = (short*)(ws + (32 << 20));  // [B,H,S,64] 8MB (scaled 0.125*log2e)
    short* Kh  = (short*)(ws + (40 << 20));  // [B,H,S,64] 8MB
    short* Vt  = (short*)(ws + (48 << 20));  // [B,H,64,S] 8MB
    short* Ctx = Abf;                        // Abf dead after QKV gemm; alias

    const float qscale = 0.125f * 1.44269504088896f;  // 1/sqrt(64) * log2(e)

    hipLaunchKernelGGL(prep, dim3(10240), dim3(256), 0, stream,
                       query, key_in, value, Abf, Wq, Wk, Wv, Wo, Wt);
    hipLaunchKernelGGL(gemmqkv, dim3(8, 64, 3), dim3(256), 0, stream,
                       Abf, Wt, bq, bk, bv, Qh, Kh, Vt, qscale);
    hipLaunchKernelGGL(attn_k, dim3(16, 32), dim3(256), 0, stream,
                       Qh, Kh, Vt, Ctx);
    hipLaunchKernelGGL(gemmo, dim3(8, 64), dim3(256), 0, stream,
                       Ctx, Wt + (3 << 20), bo, out);
}

// Round 14
// 158.863 us; speedup vs baseline: 1.0070x; 1.0070x over previous
//
#include <hip/hip_runtime.h>
#include <hip/hip_bf16.h>

// Problem constants: B=2, S=2048, D=1024, H=16, HD=64, M = B*S = 4096

typedef __attribute__((ext_vector_type(8))) short short8;    // 8 bf16 = 4 VGPR
typedef __attribute__((ext_vector_type(4))) short short4v;   // 4 bf16
typedef __attribute__((ext_vector_type(4))) float f32x4;     // 16x16 C/D frag

static __device__ __forceinline__ short f2bf(float f) {
    union { float f; unsigned u; } c; c.f = f;
    unsigned r = c.u + 0x7fff + ((c.u >> 16) & 1);   // RNE
    return (short)(r >> 16);
}

// packed f32x2 -> bf16x2 (v_cvt_pk_bf16_f32)
static __device__ __forceinline__ unsigned pk_bf16(float a, float b) {
    union { __hip_bfloat162 h; unsigned u; } c;
    c.h = __float22bfloat162_rn(make_float2(a, b));
    return c.u;
}

// async global -> LDS, 16B per lane (global_load_lds_dwordx4).
typedef const void __attribute__((address_space(1)))* gas_ptr;
typedef void __attribute__((address_space(3)))* las_ptr;
static __device__ __forceinline__ void gload16(const void* g, void* l) {
    __builtin_amdgcn_global_load_lds((gas_ptr)g, (las_ptr)l, 16, 0, 0);
}

// ---------------------------------------------------------------------------
// prep: merged f32->bf16 input conversion (3 x 4M elems) + weight transpose
// (4 x W[K][N] f32 -> Wt[N][K] bf16). One dispatch, 10240 blocks.
// ---------------------------------------------------------------------------
__global__ __launch_bounds__(256) void prep(
    const float* __restrict__ X0, const float* __restrict__ X1,
    const float* __restrict__ X2, short* __restrict__ Abf,
    const float* __restrict__ W0, const float* __restrict__ W1,
    const float* __restrict__ W2, const float* __restrict__ W3,
    short* __restrict__ Wt)
{
    __shared__ float tile[32][33];
    const int bid = blockIdx.x;
    if (bid < 6144) {           // --- tobf16: 2048 blocks per input ---
        const int zz = bid >> 11, xb = bid & 2047;
        const float* X = zz == 0 ? X0 : zz == 1 ? X1 : X2;
        short* o = Abf + ((size_t)zz << 22);
        const int i = (xb * 256 + threadIdx.x) * 8;
        const float4 a = *(const float4*)(X + i);
        const float4 b = *(const float4*)(X + i + 4);
        uint4 r;
        r.x = pk_bf16(a.x, a.y); r.y = pk_bf16(a.z, a.w);
        r.z = pk_bf16(b.x, b.y); r.w = pk_bf16(b.z, b.w);
        *(uint4*)(o + i) = r;
    } else {                    // --- wtrans: 1024 blocks per weight ---
        const int wid = bid - 6144;
        const int z = wid >> 10;
        const float* W = z == 0 ? W0 : z == 1 ? W1 : z == 2 ? W2 : W3;
        short* O = Wt + ((size_t)z << 20);
        const int k0 = (wid & 31) * 32, n0 = ((wid >> 5) & 31) * 32;
        const int tx = threadIdx.x & 31, ty = threadIdx.x >> 5;  // (32,8)
        #pragma unroll
        for (int j = 0; j < 32; j += 8)
            tile[ty + j][tx] = W[(k0 + ty + j) * 1024 + n0 + tx];
        __syncthreads();
        #pragma unroll
        for (int j = 0; j < 32; j += 8)
            O[(n0 + ty + j) * 1024 + k0 + tx] = f2bf(tile[tx][ty + j]);
    }
}

// ---------------------------------------------------------------------------
// GEMM core (BM=64, BN=128, BK=32), 4 waves, acc[2][4] of 16x16x32 frags.
// gload16-staged both operands, double-buffered, 1 barrier/K-step.
// gm0/gn0 bound as locals (macro hygiene).
// ---------------------------------------------------------------------------
#define STAGE(buf, k0) do {                                                   \
    gload16(Aa + (size_t)(gm0 + (t >> 2)) * 1024 + (k0) + (t & 3) * 8,        \
            &Al[buf][w * 512]);                                               \
    _Pragma("unroll")                                                         \
    for (int j = 0; j < 2; ++j) {                                             \
        const int c = j * 256 + t;                                            \
        gload16(Ba + (size_t)(gn0 + (c >> 2)) * 1024 + (k0) + (c & 3) * 8,    \
                &Bl[buf][j * 2048 + w * 512]);                                \
    }                                                                         \
} while (0)

#define GEMM_CORE(Aa_, Ba_, m0v, n0v)                                         \
    __shared__ short Al[2][2048];   /* [64 m][32 k] */                        \
    __shared__ short Bl[2][4096];   /* [128 n][32 k] */                       \
    const int t = threadIdx.x;                                                \
    const int gm0 = (m0v), gn0 = (n0v);                                       \
    const int lane = t & 63, w = t >> 6;                                      \
    const int lm = lane & 15, lg = lane >> 4;                                 \
    const int wr = w >> 1, wc = w & 1;                                        \
    f32x4 acc[2][4] = {};                                                     \
    STAGE(0, 0);                                                              \
    __syncthreads();                                                          \
    int buf = 0;                                                              \
    for (int kk = 0; kk < 32; ++kk) {                                         \
        if (kk < 31) STAGE(buf ^ 1, (kk + 1) * 32);                           \
        const short* Ab = Al[buf];                                            \
        const short* Bb = Bl[buf];                                            \
        short8 af[2], bfr[4];                                                 \
        _Pragma("unroll")                                                     \
        for (int mf = 0; mf < 2; ++mf)                                        \
            af[mf] = *(const short8*)(Ab + (wr * 32 + mf * 16 + lm) * 32 + lg * 8); \
        _Pragma("unroll")                                                     \
        for (int nf = 0; nf < 4; ++nf)                                        \
            bfr[nf] = *(const short8*)(Bb + (wc * 64 + nf * 16 + lm) * 32 + lg * 8); \
        _Pragma("unroll")                                                     \
        for (int mf = 0; mf < 2; ++mf)                                        \
            _Pragma("unroll")                                                 \
            for (int nf = 0; nf < 4; ++nf)                                    \
                acc[mf][nf] = __builtin_amdgcn_mfma_f32_16x16x32_bf16(        \
                    af[mf], bfr[nf], acc[mf][nf], 0, 0, 0);                   \
        __syncthreads();                                                      \
        buf ^= 1;                                                             \
    }

// ---------------------------------------------------------------------------
// Merged Q/K/V projection GEMM, bf16 A, T1 XCD-aware bijective swizzle.
// 1536 blocks = 6/CU.
// ---------------------------------------------------------------------------
__global__ __launch_bounds__(256) void gemmqkv(
    const short* __restrict__ Abase, const short* __restrict__ Wt,
    const float* __restrict__ bq, const float* __restrict__ bk,
    const float* __restrict__ bv, short* __restrict__ Qh,
    short* __restrict__ Kh, short* __restrict__ Vt, float qscale)
{
    const int flat = blockIdx.z * 512 + blockIdx.y * 8 + blockIdx.x;
    const int remap = (flat & 7) * 192 + (flat >> 3);   // 1536 % 8 == 0: bijective
    const int z = remap >> 9;
    const int rem = remap & 511;
    const int m0 = (rem >> 3) * 64, n0 = (rem & 7) * 128;

    const short* Aa = Abase + ((size_t)z << 22);
    const short* Ba = Wt + ((size_t)z << 20);
    const float* bias = z == 0 ? bq : z == 1 ? bk : bv;
    short* O = z == 0 ? Qh : z == 1 ? Kh : Vt;
    const float scale = z == 0 ? qscale : 1.0f;

    GEMM_CORE(Aa, Ba, m0, n0)

    // epilogue — D frag: col = lm (n), rows = lg*4 + i (m)
    #pragma unroll
    for (int mf = 0; mf < 2; ++mf) {
        const int mb = m0 + wr * 32 + mf * 16 + lg * 4;
        #pragma unroll
        for (int nf = 0; nf < 4; ++nf) {
            const int n = n0 + wc * 64 + nf * 16 + lm;
            const float bs = bias[n];
            if (z == 2) {   // V^T [B,H,64,S]: 4 consecutive s per lane
                short4v sv;
                #pragma unroll
                for (int i = 0; i < 4; ++i)
                    sv[i] = f2bf(acc[mf][nf][i] + bs);
                const int addr = (((mb >> 11) * 16 + (n >> 6)) * 64 + (n & 63)) * 2048 + (mb & 2047);
                *(short4v*)&O[addr] = sv;
            } else {        // head-split [B,H,S,64]
                #pragma unroll
                for (int i = 0; i < 4; ++i) {
                    const int m = mb + i;
                    const int addr = (((m >> 11) * 16 + (n >> 6)) * 2048 + (m & 2047)) * 64 + (n & 63);
                    O[addr] = f2bf(scale * (acc[mf][nf][i] + bs));
                }
            }
        }
    }
}

// ---------------------------------------------------------------------------
// Final projection: out = Ctx @ Wo^T + bo, f32 flat. 512 blocks, XCD swizzle.
// ---------------------------------------------------------------------------
__global__ __launch_bounds__(256) void gemmo(
    const short* __restrict__ Aa, const short* __restrict__ Ba,
    const float* __restrict__ bias, float* __restrict__ Out)
{
    const int flat = blockIdx.y * 8 + blockIdx.x;
    const int remap = (flat & 7) * 64 + (flat >> 3);    // 512 % 8 == 0: bijective
    const int m0 = (remap >> 3) * 64, n0 = (remap & 7) * 128;

    GEMM_CORE(Aa, Ba, m0, n0)

    #pragma unroll
    for (int mf = 0; mf < 2; ++mf) {
        const int mb = m0 + wr * 32 + mf * 16 + lg * 4;
        #pragma unroll
        for (int nf = 0; nf < 4; ++nf) {
            const int n = n0 + wc * 64 + nf * 16 + lm;
            const float bs = bias[n];
            #pragma unroll
            for (int i = 0; i < 4; ++i)
                Out[(mb + i) * 1024 + n] = acc[mf][nf][i] + bs;
        }
    }
}
#undef STAGE
#undef GEMM_CORE

// ---------------------------------------------------------------------------
// Flash attention v11 = v8's verified core with KVBLK=64 and 48KB LDS:
// 8 waves x 16 q-rows = 128 q/block (q-sharing kept — the r4->r6 win), but
// K/V tiles shrunk to [2][64][64] each (16KB+16KB) + Pl 16KB = 48KB
// -> 3 blocks/CU = 24 waves/CU (was 80KB -> 2 blocks, 50% cap, measured 33%).
// Trades 16->32 barriers for +50% resident waves; m114 wave-overlap absorbs
// barrier stalls when more blocks co-reside. 32x32 line abandoned (r12/r13:
// 32q/wave halves total waves -> 8/CU hard cap, measured 17.7% occupancy).
// Unchanged: swapped QK^T/PV 16x16 MFMA, per-lane exp2 softmax + tree
// reductions + 2 shfl, defer-max (T13), T14 early loads + late ds_write,
// XOR chunk swizzle both sides, per-wave P buffer (no barrier).
// ---------------------------------------------------------------------------
__global__ __launch_bounds__(512, 6) void attn_k(
    const short* __restrict__ Q, const short* __restrict__ K,
    const short* __restrict__ V, short* __restrict__ Ctx)
{
    __shared__ short Kl[2][64][64];   // [buf][key][d]
    __shared__ short Vl[2][64][64];   // [buf][d][key]
    __shared__ short Pl[8][16][64];
    const int t = threadIdx.x;
    const int qt = blockIdx.x, bh = blockIdx.y;
    const int lane = t & 63, w = t >> 6;   // 8 waves
    const int lm = lane & 15, lg = lane >> 4;
    const int swz = (lm & 7) << 3;          // P-buffer swizzle (shorts)
    const int swc = lm & 7;                 // K/V read chunk swizzle

    const int qrow = qt * 128 + w * 16 + lm;
    short8 qf[2];
    #pragma unroll
    for (int ks = 0; ks < 2; ++ks)
        qf[ks] = *(const short8*)(Q + ((size_t)bh * 2048 + qrow) * 64 + ks * 32 + lg * 8);

    float m_run = -3e38f, l_run = 0.f;
    f32x4 o_acc[4] = {};

    // staging: 512 threads x 1 chunk each for K and V (64 rows x 8 chunks)
    const int rk = t >> 3, ck = t & 7;
    const short* Kg = K + ((size_t)bh * 2048 + rk) * 64 + ck * 8;
    const short* Vg = V + ((size_t)bh * 64 + rk) * 2048 + ck * 8;
    const int koff = rk * 64 + (ck ^ (rk & 7)) * 8;

    {   // prologue: stage tile 0 into buffer 0
        short8 a = *(const short8*)(Kg);
        short8 c = *(const short8*)(Vg);
        *(short8*)((short*)Kl[0] + koff) = a;
        *(short8*)((short*)Vl[0] + koff) = c;
    }

    short* prow = &Pl[w][lm][0];
    int cur = 0;

    for (int kt = 0; kt < 32; ++kt) {
        __syncthreads();   // stage[cur] visible; [cur^1] free for writing

        // early-issue global loads for tile kt+1 (T14)
        short8 kn, vn;
        const bool pfn = (kt < 31);
        if (pfn) {
            kn = *(const short8*)(Kg + (size_t)(kt + 1) * 4096);   // 64 rows * 64
            vn = *(const short8*)(Vg + (kt + 1) * 64);
        }

        const short* Kc = (const short*)Kl[cur];
        const short* Vc = (const short*)Vl[cur];

        // ---- S^T = K Q^T : lane holds q=lm, keys nf*16 + lg*4 + i ----
        f32x4 sa[4] = {};
        #pragma unroll
        for (int nf = 0; nf < 4; ++nf) {
            const int rr = nf * 16 + lm;
            #pragma unroll
            for (int ks = 0; ks < 2; ++ks) {
                const short8 kf = *(const short8*)(Kc + rr * 64 + ((ks * 4 + lg) ^ swc) * 8);
                sa[nf] = __builtin_amdgcn_mfma_f32_16x16x32_bf16(kf, qf[ks], sa[nf], 0, 0, 0);
            }
        }

        // ---- max reduce: pairwise tree (fmaxf nests fuse to v_max3) ----
        float mx[4];
        #pragma unroll
        for (int nf = 0; nf < 4; ++nf)
            mx[nf] = fmaxf(fmaxf(sa[nf][0], sa[nf][1]), fmaxf(sa[nf][2], sa[nf][3]));
        float mt = fmaxf(fmaxf(mx[0], mx[1]), fmaxf(mx[2], mx[3]));
        mt = fmaxf(mt, __shfl_xor(mt, 16));
        mt = fmaxf(mt, __shfl_xor(mt, 32));
        if (__any(mt > m_run + 8.0f)) {     // defer-max (T13)
            const float mn = fmaxf(m_run, mt);
            const float alpha = exp2f(m_run - mn);
            l_run *= alpha;
            #pragma unroll
            for (int nf = 0; nf < 4; ++nf)
                #pragma unroll
                for (int i = 0; i < 4; ++i)
                    o_acc[nf][i] *= alpha;
            m_run = mn;
        }
        // exp2 + tree-structured sum
        float ps[4];
        #pragma unroll
        for (int nf = 0; nf < 4; ++nf) {
            f32x4 v = sa[nf];
            #pragma unroll
            for (int i = 0; i < 4; ++i) v[i] = exp2f(v[i] - m_run);
            sa[nf] = v;
            ps[nf] = (v[0] + v[1]) + (v[2] + v[3]);
        }
        float rs = (ps[0] + ps[1]) + (ps[2] + ps[3]);
        rs += __shfl_xor(rs, 16);
        rs += __shfl_xor(rs, 32);
        l_run += rs;

        // ---- P^T -> per-wave swizzled LDS, read back as B-frag ----
        #pragma unroll
        for (int nf = 0; nf < 4; ++nf) {
            uint2 pv;
            pv.x = pk_bf16(sa[nf][0], sa[nf][1]);
            pv.y = pk_bf16(sa[nf][2], sa[nf][3]);
            *(uint2*)(prow + ((nf * 16 + lg * 4) ^ swz)) = pv;
        }
        short8 pf[2];
        #pragma unroll
        for (int ks = 0; ks < 2; ++ks)
            pf[ks] = *(const short8*)(prow + ((ks * 32 + lg * 8) ^ swz));

        // ---- late ds_write of tile kt+1 into the other buffer ----
        if (pfn) {
            *(short8*)((short*)Kl[cur ^ 1] + koff) = kn;
            *(short8*)((short*)Vl[cur ^ 1] + koff) = vn;
        }

        // ---- ctx^T += V^T P^T : lane holds q=lm, d = nf*16 + lg*4 + i ----
        #pragma unroll
        for (int nf = 0; nf < 4; ++nf) {
            const int rr = nf * 16 + lm;
            #pragma unroll
            for (int ks = 0; ks < 2; ++ks) {
                const short8 vf = *(const short8*)(Vc + rr * 64 + ((ks * 4 + lg) ^ swc) * 8);
                o_acc[nf] = __builtin_amdgcn_mfma_f32_16x16x32_bf16(vf, pf[ks], o_acc[nf], 0, 0, 0);
            }
        }
        cur ^= 1;
    }

    // epilogue: ctx[b][q][h*64 + d] bf16, 8B vector writes
    const float inv = 1.f / l_run;
    const int b = bh >> 4, h = bh & 15;
    short* outp = Ctx + ((size_t)b * 2048 + qrow) * 1024 + h * 64 + lg * 4;
    #pragma unroll
    for (int nf = 0; nf < 4; ++nf) {
        uint2 pk;
        pk.x = pk_bf16(o_acc[nf][0] * inv, o_acc[nf][1] * inv);
        pk.y = pk_bf16(o_acc[nf][2] * inv, o_acc[nf][3] * inv);
        *(uint2*)(outp + nf * 16) = pk;
    }
}

// ---------------------------------------------------------------------------
extern "C" void kernel_launch(void* const* d_in, const int* in_sizes, int n_in,
                              void* d_out, int out_size, void* d_ws, size_t ws_size,
                              hipStream_t stream)
{
    const float* query  = (const float*)d_in[0];
    const float* key_in = (const float*)d_in[1];
    const float* value  = (const float*)d_in[2];
    const float* Wq = (const float*)d_in[3];
    const float* bq = (const float*)d_in[4];
    const float* Wk = (const float*)d_in[5];
    const float* bk = (const float*)d_in[6];
    const float* Wv = (const float*)d_in[7];
    const float* bv = (const float*)d_in[8];
    const float* Wo = (const float*)d_in[9];
    const float* bo = (const float*)d_in[10];
    float* out = (float*)d_out;

    char* ws = (char*)d_ws;
    short* Wt  = (short*)(ws);               // 4 x 2MB transposed bf16 weights
    short* Abf = (short*)(ws + (8  << 20));  // 3 x 8MB bf16 inputs (q,k,v)
    short* Qh  = (short*)(ws + (32 << 20));  // [B,H,S,64] 8MB (scaled 0.125*log2e)
    short* Kh  = (short*)(ws + (40 << 20));  // [B,H,S,64] 8MB
    short* Vt  = (short*)(ws + (48 << 20));  // [B,H,64,S] 8MB
    short* Ctx = Abf;                        // Abf dead after QKV gemm; alias

    const float qscale = 0.125f * 1.44269504088896f;  // 1/sqrt(64) * log2(e)

    hipLaunchKernelGGL(prep, dim3(10240), dim3(256), 0, stream,
                       query, key_in, value, Abf, Wq, Wk, Wv, Wo, Wt);
    hipLaunchKernelGGL(gemmqkv, dim3(8, 64, 3), dim3(256), 0, stream,
                       Abf, Wt, bq, bk, bv, Qh, Kh, Vt, qscale);
    hipLaunchKernelGGL(attn_k, dim3(16, 32), dim3(512), 0, stream,
                       Qh, Kh, Vt, Ctx);
    hipLaunchKernelGGL(gemmo, dim3(8, 64), dim3(256), 0, stream,
                       Ctx, Wt + (3 << 20), bo, out);
}

// Round 15
// 154.251 us; speedup vs baseline: 1.0371x; 1.0299x over previous
//
#include <hip/hip_runtime.h>
#include <hip/hip_bf16.h>

// Problem constants: B=2, S=2048, D=1024, H=16, HD=64, M = B*S = 4096

typedef __attribute__((ext_vector_type(8))) short short8;    // 8 bf16 = 4 VGPR
typedef __attribute__((ext_vector_type(4))) short short4v;   // 4 bf16
typedef __attribute__((ext_vector_type(4))) float f32x4;     // 16x16 C/D frag

static __device__ __forceinline__ short f2bf(float f) {
    union { float f; unsigned u; } c; c.f = f;
    unsigned r = c.u + 0x7fff + ((c.u >> 16) & 1);   // RNE
    return (short)(r >> 16);
}

// packed f32x2 -> bf16x2 (v_cvt_pk_bf16_f32)
static __device__ __forceinline__ unsigned pk_bf16(float a, float b) {
    union { __hip_bfloat162 h; unsigned u; } c;
    c.h = __float22bfloat162_rn(make_float2(a, b));
    return c.u;
}

// async global -> LDS, 16B per lane (global_load_lds_dwordx4).
typedef const void __attribute__((address_space(1)))* gas_ptr;
typedef void __attribute__((address_space(3)))* las_ptr;
static __device__ __forceinline__ void gload16(const void* g, void* l) {
    __builtin_amdgcn_global_load_lds((gas_ptr)g, (las_ptr)l, 16, 0, 0);
}

// ---------------------------------------------------------------------------
// prep: merged f32->bf16 input conversion (3 x 4M elems) + weight transpose
// (4 x W[K][N] f32 -> Wt[N][K] bf16). One dispatch, 10240 blocks.
// ---------------------------------------------------------------------------
__global__ __launch_bounds__(256) void prep(
    const float* __restrict__ X0, const float* __restrict__ X1,
    const float* __restrict__ X2, short* __restrict__ Abf,
    const float* __restrict__ W0, const float* __restrict__ W1,
    const float* __restrict__ W2, const float* __restrict__ W3,
    short* __restrict__ Wt)
{
    __shared__ float tile[32][33];
    const int bid = blockIdx.x;
    if (bid < 6144) {           // --- tobf16: 2048 blocks per input ---
        const int zz = bid >> 11, xb = bid & 2047;
        const float* X = zz == 0 ? X0 : zz == 1 ? X1 : X2;
        short* o = Abf + ((size_t)zz << 22);
        const int i = (xb * 256 + threadIdx.x) * 8;
        const float4 a = *(const float4*)(X + i);
        const float4 b = *(const float4*)(X + i + 4);
        uint4 r;
        r.x = pk_bf16(a.x, a.y); r.y = pk_bf16(a.z, a.w);
        r.z = pk_bf16(b.x, b.y); r.w = pk_bf16(b.z, b.w);
        *(uint4*)(o + i) = r;
    } else {                    // --- wtrans: 1024 blocks per weight ---
        const int wid = bid - 6144;
        const int z = wid >> 10;
        const float* W = z == 0 ? W0 : z == 1 ? W1 : z == 2 ? W2 : W3;
        short* O = Wt + ((size_t)z << 20);
        const int k0 = (wid & 31) * 32, n0 = ((wid >> 5) & 31) * 32;
        const int tx = threadIdx.x & 31, ty = threadIdx.x >> 5;  // (32,8)
        #pragma unroll
        for (int j = 0; j < 32; j += 8)
            tile[ty + j][tx] = W[(k0 + ty + j) * 1024 + n0 + tx];
        __syncthreads();
        #pragma unroll
        for (int j = 0; j < 32; j += 8)
            O[(n0 + ty + j) * 1024 + k0 + tx] = f2bf(tile[tx][ty + j]);
    }
}

// ---------------------------------------------------------------------------
// GEMM core (BM=64, BN=128, BK=32), 4 waves, acc[2][4] of 16x16x32 frags.
// gload16-staged both operands, double-buffered, 1 barrier/K-step.
// gm0/gn0 bound as locals (macro hygiene).
// ---------------------------------------------------------------------------
#define STAGE(buf, k0) do {                                                   \
    gload16(Aa + (size_t)(gm0 + (t >> 2)) * 1024 + (k0) + (t & 3) * 8,        \
            &Al[buf][w * 512]);                                               \
    _Pragma("unroll")                                                         \
    for (int j = 0; j < 2; ++j) {                                             \
        const int c = j * 256 + t;                                            \
        gload16(Ba + (size_t)(gn0 + (c >> 2)) * 1024 + (k0) + (c & 3) * 8,    \
                &Bl[buf][j * 2048 + w * 512]);                                \
    }                                                                         \
} while (0)

#define GEMM_CORE(Aa_, Ba_, m0v, n0v)                                         \
    __shared__ short Al[2][2048];   /* [64 m][32 k] */                        \
    __shared__ short Bl[2][4096];   /* [128 n][32 k] */                       \
    const int t = threadIdx.x;                                                \
    const int gm0 = (m0v), gn0 = (n0v);                                       \
    const int lane = t & 63, w = t >> 6;                                      \
    const int lm = lane & 15, lg = lane >> 4;                                 \
    const int wr = w >> 1, wc = w & 1;                                        \
    f32x4 acc[2][4] = {};                                                     \
    STAGE(0, 0);                                                              \
    __syncthreads();                                                          \
    int buf = 0;                                                              \
    for (int kk = 0; kk < 32; ++kk) {                                         \
        if (kk < 31) STAGE(buf ^ 1, (kk + 1) * 32);                           \
        const short* Ab = Al[buf];                                            \
        const short* Bb = Bl[buf];                                            \
        short8 af[2], bfr[4];                                                 \
        _Pragma("unroll")                                                     \
        for (int mf = 0; mf < 2; ++mf)                                        \
            af[mf] = *(const short8*)(Ab + (wr * 32 + mf * 16 + lm) * 32 + lg * 8); \
        _Pragma("unroll")                                                     \
        for (int nf = 0; nf < 4; ++nf)                                        \
            bfr[nf] = *(const short8*)(Bb + (wc * 64 + nf * 16 + lm) * 32 + lg * 8); \
        _Pragma("unroll")                                                     \
        for (int mf = 0; mf < 2; ++mf)                                        \
            _Pragma("unroll")                                                 \
            for (int nf = 0; nf < 4; ++nf)                                    \
                acc[mf][nf] = __builtin_amdgcn_mfma_f32_16x16x32_bf16(        \
                    af[mf], bfr[nf], acc[mf][nf], 0, 0, 0);                   \
        __syncthreads();                                                      \
        buf ^= 1;                                                             \
    }

// ---------------------------------------------------------------------------
// Merged Q/K/V projection GEMM, bf16 A, T1 XCD-aware bijective swizzle.
// 1536 blocks = 6/CU.
// ---------------------------------------------------------------------------
__global__ __launch_bounds__(256) void gemmqkv(
    const short* __restrict__ Abase, const short* __restrict__ Wt,
    const float* __restrict__ bq, const float* __restrict__ bk,
    const float* __restrict__ bv, short* __restrict__ Qh,
    short* __restrict__ Kh, short* __restrict__ Vt, float qscale)
{
    const int flat = blockIdx.z * 512 + blockIdx.y * 8 + blockIdx.x;
    const int remap = (flat & 7) * 192 + (flat >> 3);   // 1536 % 8 == 0: bijective
    const int z = remap >> 9;
    const int rem = remap & 511;
    const int m0 = (rem >> 3) * 64, n0 = (rem & 7) * 128;

    const short* Aa = Abase + ((size_t)z << 22);
    const short* Ba = Wt + ((size_t)z << 20);
    const float* bias = z == 0 ? bq : z == 1 ? bk : bv;
    short* O = z == 0 ? Qh : z == 1 ? Kh : Vt;
    const float scale = z == 0 ? qscale : 1.0f;

    GEMM_CORE(Aa, Ba, m0, n0)

    // epilogue — D frag: col = lm (n), rows = lg*4 + i (m)
    #pragma unroll
    for (int mf = 0; mf < 2; ++mf) {
        const int mb = m0 + wr * 32 + mf * 16 + lg * 4;
        #pragma unroll
        for (int nf = 0; nf < 4; ++nf) {
            const int n = n0 + wc * 64 + nf * 16 + lm;
            const float bs = bias[n];
            if (z == 2) {   // V^T [B,H,64,S]: 4 consecutive s per lane
                short4v sv;
                #pragma unroll
                for (int i = 0; i < 4; ++i)
                    sv[i] = f2bf(acc[mf][nf][i] + bs);
                const int addr = (((mb >> 11) * 16 + (n >> 6)) * 64 + (n & 63)) * 2048 + (mb & 2047);
                *(short4v*)&O[addr] = sv;
            } else {        // head-split [B,H,S,64]
                #pragma unroll
                for (int i = 0; i < 4; ++i) {
                    const int m = mb + i;
                    const int addr = (((m >> 11) * 16 + (n >> 6)) * 2048 + (m & 2047)) * 64 + (n & 63);
                    O[addr] = f2bf(scale * (acc[mf][nf][i] + bs));
                }
            }
        }
    }
}

// ---------------------------------------------------------------------------
// Final projection: out = Ctx @ Wo^T + bo, f32 flat. 512 blocks, XCD swizzle.
// ---------------------------------------------------------------------------
__global__ __launch_bounds__(256) void gemmo(
    const short* __restrict__ Aa, const short* __restrict__ Ba,
    const float* __restrict__ bias, float* __restrict__ Out)
{
    const int flat = blockIdx.y * 8 + blockIdx.x;
    const int remap = (flat & 7) * 64 + (flat >> 3);    // 512 % 8 == 0: bijective
    const int m0 = (remap >> 3) * 64, n0 = (remap & 7) * 128;

    GEMM_CORE(Aa, Ba, m0, n0)

    #pragma unroll
    for (int mf = 0; mf < 2; ++mf) {
        const int mb = m0 + wr * 32 + mf * 16 + lg * 4;
        #pragma unroll
        for (int nf = 0; nf < 4; ++nf) {
            const int n = n0 + wc * 64 + nf * 16 + lm;
            const float bs = bias[n];
            #pragma unroll
            for (int i = 0; i < 4; ++i)
                Out[(mb + i) * 1024 + n] = acc[mf][nf][i] + bs;
        }
    }
}
#undef STAGE
#undef GEMM_CORE

// ---------------------------------------------------------------------------
// Flash attention v12 = r11's v8 core (best measured, 74 µs) + XCD-chunked
// block remap. v8: 8 waves x 16 q-rows = 128 q/block, KVBLK=128/barrier,
// V tile as two [64][64] halves, XOR chunk swizzle, double-buffer + T14,
// 1 barrier/tile, swapped QK^T/PV, exp2 softmax, defer-max, tree reductions.
// NEW: flat 512-block grid remapped so each XCD owns a contiguous 64-block
// chunk = 4 whole bh's (4 x 512KB K+V = 2MB < 4MB XCD L2) — r11 measured
// FETCH 70MB vs 24MB ideal because qt-blocks of one bh spread over all 8
// XCDs, each missing L2 on the same K/V. v11's KVBLK=64 occupancy experiment
// REVERTED (static cap rose but realized occupancy didn't; 2x barriers lost).
// ---------------------------------------------------------------------------
__global__ __launch_bounds__(512, 4) void attn_k(
    const short* __restrict__ Q, const short* __restrict__ K,
    const short* __restrict__ V, short* __restrict__ Ctx)
{
    __shared__ short Kl[2][128][64];
    __shared__ short Vl[2][2][64][64];   // [buf][key-half][d-row][key-chunk]
    __shared__ short Pl[8][16][64];
    const int t = threadIdx.x;
    const int flat = blockIdx.y * 16 + blockIdx.x;
    const int remap = (flat & 7) * 64 + (flat >> 3);   // 512 % 8 == 0: bijective
    const int qt = remap & 15, bh = remap >> 4;        // XCD c -> bh in [4c,4c+4)
    const int lane = t & 63, w = t >> 6;   // 8 waves
    const int lm = lane & 15, lg = lane >> 4;
    const int swz = (lm & 7) << 3;          // P-buffer swizzle (shorts)
    const int swc = lm & 7;                 // K/V read chunk swizzle

    const int qrow = qt * 128 + w * 16 + lm;
    short8 qf[2];
    #pragma unroll
    for (int ks = 0; ks < 2; ++ks)
        qf[ks] = *(const short8*)(Q + ((size_t)bh * 2048 + qrow) * 64 + ks * 32 + lg * 8);

    float m_run = -3e38f, l_run = 0.f;
    f32x4 o_acc[4] = {};

    const int rk = t >> 2, ck = t & 3;
    const int rv = t >> 3, cv = t & 7;
    const short* Kg = K + ((size_t)bh * 2048 + rk) * 64 + ck * 16;
    const short* Vg = V + ((size_t)bh * 64 + rv) * 2048 + cv * 16;
    const int koff0 = rk * 64 + ((ck * 2) ^ (rk & 7)) * 8;
    const int koff1 = rk * 64 + ((ck * 2 + 1) ^ (rk & 7)) * 8;
    const int vhalf = (cv >> 2) * 4096;
    const int voff0 = vhalf + rv * 64 + (((cv * 2) & 7) ^ (rv & 7)) * 8;
    const int voff1 = vhalf + rv * 64 + (((cv * 2 + 1) & 7) ^ (rv & 7)) * 8;

    {   // prologue: stage tile 0 into buffer 0
        short8 a = *(const short8*)(Kg);
        short8 b = *(const short8*)(Kg + 8);
        short8 c = *(const short8*)(Vg);
        short8 d = *(const short8*)(Vg + 8);
        *(short8*)((short*)Kl[0] + koff0) = a;
        *(short8*)((short*)Kl[0] + koff1) = b;
        *(short8*)((short*)Vl[0] + voff0) = c;
        *(short8*)((short*)Vl[0] + voff1) = d;
    }

    short* prow = &Pl[w][lm][0];
    int cur = 0;

    for (int kt = 0; kt < 16; ++kt) {
        __syncthreads();   // stage[cur] visible; [cur^1] free for writing

        // early-issue global loads for tile kt+1 (T14)
        short8 kn0, kn1, vn0, vn1;
        const bool pfn = (kt < 15);
        if (pfn) {
            const short* Kgn = Kg + (size_t)(kt + 1) * 8192;   // 128 rows * 64
            const short* Vgn = Vg + (kt + 1) * 128;
            kn0 = *(const short8*)(Kgn);
            kn1 = *(const short8*)(Kgn + 8);
            vn0 = *(const short8*)(Vgn);
            vn1 = *(const short8*)(Vgn + 8);
        }

        const short* Kc = (const short*)Kl[cur];
        const short* Vc = (const short*)Vl[cur];

        // ---- S^T = K Q^T, BOTH halves: lane holds q=lm, 32 key-vals ----
        f32x4 sa[2][4] = {};
        #pragma unroll
        for (int h = 0; h < 2; ++h)
            #pragma unroll
            for (int nf = 0; nf < 4; ++nf) {
                const int rr = h * 64 + nf * 16 + lm;
                #pragma unroll
                for (int ks = 0; ks < 2; ++ks) {
                    const short8 kf = *(const short8*)(Kc + rr * 64 + ((ks * 4 + lg) ^ swc) * 8);
                    sa[h][nf] = __builtin_amdgcn_mfma_f32_16x16x32_bf16(kf, qf[ks], sa[h][nf], 0, 0, 0);
                }
            }

        // ---- max reduce: pairwise tree (fmaxf nests fuse to v_max3) ----
        float mx[8];
        #pragma unroll
        for (int h = 0; h < 2; ++h)
            #pragma unroll
            for (int nf = 0; nf < 4; ++nf) {
                const f32x4 v = sa[h][nf];
                mx[h * 4 + nf] = fmaxf(fmaxf(v[0], v[1]), fmaxf(v[2], v[3]));
            }
        float mt = fmaxf(fmaxf(fmaxf(mx[0], mx[1]), fmaxf(mx[2], mx[3])),
                         fmaxf(fmaxf(mx[4], mx[5]), fmaxf(mx[6], mx[7])));
        mt = fmaxf(mt, __shfl_xor(mt, 16));
        mt = fmaxf(mt, __shfl_xor(mt, 32));
        if (__any(mt > m_run + 8.0f)) {     // defer-max (T13)
            const float mn = fmaxf(m_run, mt);
            const float alpha = exp2f(m_run - mn);
            l_run *= alpha;
            #pragma unroll
            for (int nf = 0; nf < 4; ++nf)
                #pragma unroll
                for (int i = 0; i < 4; ++i)
                    o_acc[nf][i] *= alpha;
            m_run = mn;
        }
        // exp2 + tree-structured sum (8 frag-partials -> 3-level tree)
        float ps[8];
        #pragma unroll
        for (int h = 0; h < 2; ++h)
            #pragma unroll
            for (int nf = 0; nf < 4; ++nf) {
                f32x4 v = sa[h][nf];
                #pragma unroll
                for (int i = 0; i < 4; ++i) v[i] = exp2f(v[i] - m_run);
                sa[h][nf] = v;
                ps[h * 4 + nf] = (v[0] + v[1]) + (v[2] + v[3]);
            }
        float rs = ((ps[0] + ps[1]) + (ps[2] + ps[3])) +
                   ((ps[4] + ps[5]) + (ps[6] + ps[7]));
        rs += __shfl_xor(rs, 16);
        rs += __shfl_xor(rs, 32);
        l_run += rs;

        // ---- per key-half: P-pack -> pf -> PV (P buffer reused) ----
        #pragma unroll
        for (int h = 0; h < 2; ++h) {
            #pragma unroll
            for (int nf = 0; nf < 4; ++nf) {
                uint2 pv;
                pv.x = pk_bf16(sa[h][nf][0], sa[h][nf][1]);
                pv.y = pk_bf16(sa[h][nf][2], sa[h][nf][3]);
                *(uint2*)(prow + ((nf * 16 + lg * 4) ^ swz)) = pv;
            }
            short8 pf[2];
            #pragma unroll
            for (int ks = 0; ks < 2; ++ks)
                pf[ks] = *(const short8*)(prow + ((ks * 32 + lg * 8) ^ swz));

            // late ds_write of tile kt+1 (between the two PV halves)
            if (h == 0 && pfn) {
                short* Kn = (short*)Kl[cur ^ 1];
                short* Vn = (short*)Vl[cur ^ 1];
                *(short8*)(Kn + koff0) = kn0;
                *(short8*)(Kn + koff1) = kn1;
                *(short8*)(Vn + voff0) = vn0;
                *(short8*)(Vn + voff1) = vn1;
            }

            // ctx^T += V^T P^T : lane holds q=lm, d = nf*16+lg*4+i
            #pragma unroll
            for (int nf = 0; nf < 4; ++nf) {
                const int rr = nf * 16 + lm;
                #pragma unroll
                for (int ks = 0; ks < 2; ++ks) {
                    const short8 vf = *(const short8*)(Vc + h * 4096 + rr * 64 + ((ks * 4 + lg) ^ swc) * 8);
                    o_acc[nf] = __builtin_amdgcn_mfma_f32_16x16x32_bf16(vf, pf[ks], o_acc[nf], 0, 0, 0);
                }
            }
        }
        cur ^= 1;
    }

    // epilogue: ctx[b][q][h*64 + d] bf16, 8B vector writes
    const float inv = 1.f / l_run;
    const int b = bh >> 4, h = bh & 15;
    short* outp = Ctx + ((size_t)b * 2048 + qrow) * 1024 + h * 64 + lg * 4;
    #pragma unroll
    for (int nf = 0; nf < 4; ++nf) {
        uint2 pk;
        pk.x = pk_bf16(o_acc[nf][0] * inv, o_acc[nf][1] * inv);
        pk.y = pk_bf16(o_acc[nf][2] * inv, o_acc[nf][3] * inv);
        *(uint2*)(outp + nf * 16) = pk;
    }
}

// ---------------------------------------------------------------------------
extern "C" void kernel_launch(void* const* d_in, const int* in_sizes, int n_in,
                              void* d_out, int out_size, void* d_ws, size_t ws_size,
                              hipStream_t stream)
{
    const float* query  = (const float*)d_in[0];
    const float* key_in = (const float*)d_in[1];
    const float* value  = (const float*)d_in[2];
    const float* Wq = (const float*)d_in[3];
    const float* bq = (const float*)d_in[4];
    const float* Wk = (const float*)d_in[5];
    const float* bk = (const float*)d_in[6];
    const float* Wv = (const float*)d_in[7];
    const float* bv = (const float*)d_in[8];
    const float* Wo = (const float*)d_in[9];
    const float* bo = (const float*)d_in[10];
    float* out = (float*)d_out;

    char* ws = (char*)d_ws;
    short* Wt  = (short*)(ws);               // 4 x 2MB transposed bf16 weights
    short* Abf = (short*)(ws + (8  << 20));  // 3 x 8MB bf16 inputs (q,k,v)
    short* Qh  = (short*)(ws + (32 << 20));  // [B,H,S,64] 8MB (scaled 0.125*log2e)
    short* Kh  = (short*)(ws + (40 << 20));  // [B,H,S,64] 8MB
    short* Vt  = (short*)(ws + (48 << 20));  // [B,H,64,S] 8MB
    short* Ctx = Abf;                        // Abf dead after QKV gemm; alias

    const float qscale = 0.125f * 1.44269504088896f;  // 1/sqrt(64) * log2(e)

    hipLaunchKernelGGL(prep, dim3(10240), dim3(256), 0, stream,
                       query, key_in, value, Abf, Wq, Wk, Wv, Wo, Wt);
    hipLaunchKernelGGL(gemmqkv, dim3(8, 64, 3), dim3(256), 0, stream,
                       Abf, Wt, bq, bk, bv, Qh, Kh, Vt, qscale);
    hipLaunchKernelGGL(attn_k, dim3(16, 32), dim3(512), 0, stream,
                       Qh, Kh, Vt, Ctx);
    hipLaunchKernelGGL(gemmo, dim3(8, 64), dim3(256), 0, stream,
                       Ctx, Wt + (3 << 20), bo, out);
}

// Round 16
// 138.069 us; speedup vs baseline: 1.1587x; 1.1172x over previous
//
#include <hip/hip_runtime.h>
#include <hip/hip_bf16.h>

// Problem constants: B=2, S=2048, D=1024, H=16, HD=64, M = B*S = 4096

typedef __attribute__((ext_vector_type(8))) short short8;    // 8 bf16 = 4 VGPR
typedef __attribute__((ext_vector_type(4))) short short4v;   // 4 bf16
typedef __attribute__((ext_vector_type(4))) float f32x4;     // 16x16 C/D frag

static __device__ __forceinline__ short f2bf(float f) {
    union { float f; unsigned u; } c; c.f = f;
    unsigned r = c.u + 0x7fff + ((c.u >> 16) & 1);   // RNE
    return (short)(r >> 16);
}

// packed f32x2 -> bf16x2 (v_cvt_pk_bf16_f32)
static __device__ __forceinline__ unsigned pk_bf16(float a, float b) {
    union { __hip_bfloat162 h; unsigned u; } c;
    c.h = __float22bfloat162_rn(make_float2(a, b));
    return c.u;
}

// async global -> LDS, 16B per lane (global_load_lds_dwordx4).
typedef const void __attribute__((address_space(1)))* gas_ptr;
typedef void __attribute__((address_space(3)))* las_ptr;
static __device__ __forceinline__ void gload16(const void* g, void* l) {
    __builtin_amdgcn_global_load_lds((gas_ptr)g, (las_ptr)l, 16, 0, 0);
}

// ---------------------------------------------------------------------------
// prep: merged f32->bf16 input conversion (3 x 4M elems) + weight transpose
// (4 x W[K][N] f32 -> Wt[N][K] bf16). One dispatch, 10240 blocks.
// ---------------------------------------------------------------------------
__global__ __launch_bounds__(256) void prep(
    const float* __restrict__ X0, const float* __restrict__ X1,
    const float* __restrict__ X2, short* __restrict__ Abf,
    const float* __restrict__ W0, const float* __restrict__ W1,
    const float* __restrict__ W2, const float* __restrict__ W3,
    short* __restrict__ Wt)
{
    __shared__ float tile[32][33];
    const int bid = blockIdx.x;
    if (bid < 6144) {           // --- tobf16: 2048 blocks per input ---
        const int zz = bid >> 11, xb = bid & 2047;
        const float* X = zz == 0 ? X0 : zz == 1 ? X1 : X2;
        short* o = Abf + ((size_t)zz << 22);
        const int i = (xb * 256 + threadIdx.x) * 8;
        const float4 a = *(const float4*)(X + i);
        const float4 b = *(const float4*)(X + i + 4);
        uint4 r;
        r.x = pk_bf16(a.x, a.y); r.y = pk_bf16(a.z, a.w);
        r.z = pk_bf16(b.x, b.y); r.w = pk_bf16(b.z, b.w);
        *(uint4*)(o + i) = r;
    } else {                    // --- wtrans: 1024 blocks per weight ---
        const int wid = bid - 6144;
        const int z = wid >> 10;
        const float* W = z == 0 ? W0 : z == 1 ? W1 : z == 2 ? W2 : W3;
        short* O = Wt + ((size_t)z << 20);
        const int k0 = (wid & 31) * 32, n0 = ((wid >> 5) & 31) * 32;
        const int tx = threadIdx.x & 31, ty = threadIdx.x >> 5;  // (32,8)
        #pragma unroll
        for (int j = 0; j < 32; j += 8)
            tile[ty + j][tx] = W[(k0 + ty + j) * 1024 + n0 + tx];
        __syncthreads();
        #pragma unroll
        for (int j = 0; j < 32; j += 8)
            O[(n0 + ty + j) * 1024 + k0 + tx] = f2bf(tile[tx][ty + j]);
    }
}

// ---------------------------------------------------------------------------
// Merged Q/K/V projection GEMM — m97 128x128 structure (upgraded from 64x128):
// BM=BN=128, BK=32, 4 waves each owning a 64x64 quadrant (acc[4][4] of
// 16x16x32 frags -> 16 MFMA/wave/K-step, 2x the old 8; staging per MFMA
// halves — the m93->m97 ladder step, +69% there). Both operands staged via
// global_load_lds dwordx4 (4 chunks/thread), double-buffered, 1 barrier/
// K-step. Grid (8,32,3) = 768 blocks = 3 blocks/CU (VGPR-limited, m97-like);
// T1 bijective XCD swizzle (768%8==0, 96-block chunks: each z's 2MB weight
// panel XCD-L2-resident). launch_bounds(256,3) caps VGPR at ~170.
// ---------------------------------------------------------------------------
__global__ __launch_bounds__(256, 3) void gemmqkv(
    const short* __restrict__ Abase, const short* __restrict__ Wt,
    const float* __restrict__ bq, const float* __restrict__ bk,
    const float* __restrict__ bv, short* __restrict__ Qh,
    short* __restrict__ Kh, short* __restrict__ Vt, float qscale)
{
    __shared__ short Al[2][4096];   // [128 m][32 k]
    __shared__ short Bl[2][4096];   // [128 n][32 k]
    const int flat = blockIdx.z * 256 + blockIdx.y * 8 + blockIdx.x;
    const int remap = (flat & 7) * 96 + (flat >> 3);   // 768 % 8 == 0: bijective
    const int z = remap >> 8;
    const int rem = remap & 255;
    const int m0 = (rem >> 3) * 128, n0 = (rem & 7) * 128;

    const short* Aa = Abase + ((size_t)z << 22);
    const short* Ba = Wt + ((size_t)z << 20);
    const float* bias = z == 0 ? bq : z == 1 ? bk : bv;
    short* O = z == 0 ? Qh : z == 1 ? Kh : Vt;
    const float scale = z == 0 ? qscale : 1.0f;

    const int t = threadIdx.x;
    const int lane = t & 63, w = t >> 6;
    const int lm = lane & 15, lg = lane >> 4;
    const int wr = w >> 1, wc = w & 1;

    // stage both 128x32 tiles: 512 chunks of 16B each; thread t covers
    // chunks j*256+t (row = c>>2, k-chunk = c&3); wave-linear LDS dest.
    #define STAGEQ(buf, k0) do {                                              \
        _Pragma("unroll")                                                     \
        for (int j = 0; j < 2; ++j) {                                         \
            const int c = j * 256 + t;                                        \
            gload16(Aa + (size_t)(m0 + (c >> 2)) * 1024 + (k0) + (c & 3) * 8, \
                    &Al[buf][j * 2048 + w * 512]);                            \
            gload16(Ba + (size_t)(n0 + (c >> 2)) * 1024 + (k0) + (c & 3) * 8, \
                    &Bl[buf][j * 2048 + w * 512]);                            \
        }                                                                     \
    } while (0)

    f32x4 acc[4][4] = {};
    STAGEQ(0, 0);
    __syncthreads();

    int buf = 0;
    for (int kk = 0; kk < 32; ++kk) {
        if (kk < 31) STAGEQ(buf ^ 1, (kk + 1) * 32);
        const short* Ab = Al[buf];
        const short* Bb = Bl[buf];
        short8 af[4], bfr[4];
        #pragma unroll
        for (int mf = 0; mf < 4; ++mf)
            af[mf] = *(const short8*)(Ab + (wr * 64 + mf * 16 + lm) * 32 + lg * 8);
        #pragma unroll
        for (int nf = 0; nf < 4; ++nf)
            bfr[nf] = *(const short8*)(Bb + (wc * 64 + nf * 16 + lm) * 32 + lg * 8);
        #pragma unroll
        for (int mf = 0; mf < 4; ++mf)
            #pragma unroll
            for (int nf = 0; nf < 4; ++nf)
                acc[mf][nf] = __builtin_amdgcn_mfma_f32_16x16x32_bf16(
                    af[mf], bfr[nf], acc[mf][nf], 0, 0, 0);
        __syncthreads();
        buf ^= 1;
    }
    #undef STAGEQ

    // epilogue — D frag: col = lm (n), rows = lg*4 + i (m)
    #pragma unroll
    for (int mf = 0; mf < 4; ++mf) {
        const int mb = m0 + wr * 64 + mf * 16 + lg * 4;
        #pragma unroll
        for (int nf = 0; nf < 4; ++nf) {
            const int n = n0 + wc * 64 + nf * 16 + lm;
            const float bs = bias[n];
            if (z == 2) {   // V^T [B,H,64,S]: 4 consecutive s per lane
                short4v sv;
                #pragma unroll
                for (int i = 0; i < 4; ++i)
                    sv[i] = f2bf(acc[mf][nf][i] + bs);
                const int addr = (((mb >> 11) * 16 + (n >> 6)) * 64 + (n & 63)) * 2048 + (mb & 2047);
                *(short4v*)&O[addr] = sv;
            } else {        // head-split [B,H,S,64]
                #pragma unroll
                for (int i = 0; i < 4; ++i) {
                    const int m = mb + i;
                    const int addr = (((m >> 11) * 16 + (n >> 6)) * 2048 + (m & 2047)) * 64 + (n & 63);
                    O[addr] = f2bf(scale * (acc[mf][nf][i] + bs));
                }
            }
        }
    }
}

// ---------------------------------------------------------------------------
// GEMM core (BM=64, BN=128, BK=32), 4 waves — kept for gemmo (512 blocks =
// 2/CU; a 128^2 gemmo would be 256 blocks = 1/CU, the r4 starvation regime).
// ---------------------------------------------------------------------------
#define STAGE(buf, k0) do {                                                   \
    gload16(Aa + (size_t)(gm0 + (t >> 2)) * 1024 + (k0) + (t & 3) * 8,        \
            &Al[buf][w * 512]);                                               \
    _Pragma("unroll")                                                         \
    for (int j = 0; j < 2; ++j) {                                             \
        const int c = j * 256 + t;                                            \
        gload16(Ba + (size_t)(gn0 + (c >> 2)) * 1024 + (k0) + (c & 3) * 8,    \
                &Bl[buf][j * 2048 + w * 512]);                                \
    }                                                                         \
} while (0)

#define GEMM_CORE(Aa_, Ba_, m0v, n0v)                                         \
    __shared__ short Al[2][2048];   /* [64 m][32 k] */                        \
    __shared__ short Bl[2][4096];   /* [128 n][32 k] */                       \
    const int t = threadIdx.x;                                                \
    const int gm0 = (m0v), gn0 = (n0v);                                       \
    const int lane = t & 63, w = t >> 6;                                      \
    const int lm = lane & 15, lg = lane >> 4;                                 \
    const int wr = w >> 1, wc = w & 1;                                        \
    f32x4 acc[2][4] = {};                                                     \
    STAGE(0, 0);                                                              \
    __syncthreads();                                                          \
    int buf = 0;                                                              \
    for (int kk = 0; kk < 32; ++kk) {                                         \
        if (kk < 31) STAGE(buf ^ 1, (kk + 1) * 32);                           \
        const short* Ab = Al[buf];                                            \
        const short* Bb = Bl[buf];                                            \
        short8 af[2], bfr[4];                                                 \
        _Pragma("unroll")                                                     \
        for (int mf = 0; mf < 2; ++mf)                                        \
            af[mf] = *(const short8*)(Ab + (wr * 32 + mf * 16 + lm) * 32 + lg * 8); \
        _Pragma("unroll")                                                     \
        for (int nf = 0; nf < 4; ++nf)                                        \
            bfr[nf] = *(const short8*)(Bb + (wc * 64 + nf * 16 + lm) * 32 + lg * 8); \
        _Pragma("unroll")                                                     \
        for (int mf = 0; mf < 2; ++mf)                                        \
            _Pragma("unroll")                                                 \
            for (int nf = 0; nf < 4; ++nf)                                    \
                acc[mf][nf] = __builtin_amdgcn_mfma_f32_16x16x32_bf16(        \
                    af[mf], bfr[nf], acc[mf][nf], 0, 0, 0);                   \
        __syncthreads();                                                      \
        buf ^= 1;                                                             \
    }

// ---------------------------------------------------------------------------
// Final projection: out = Ctx @ Wo^T + bo, f32 flat. 512 blocks, XCD swizzle.
// ---------------------------------------------------------------------------
__global__ __launch_bounds__(256) void gemmo(
    const short* __restrict__ Aa, const short* __restrict__ Ba,
    const float* __restrict__ bias, float* __restrict__ Out)
{
    const int flat = blockIdx.y * 8 + blockIdx.x;
    const int remap = (flat & 7) * 64 + (flat >> 3);    // 512 % 8 == 0: bijective
    const int m0 = (remap >> 3) * 64, n0 = (remap & 7) * 128;

    GEMM_CORE(Aa, Ba, m0, n0)

    #pragma unroll
    for (int mf = 0; mf < 2; ++mf) {
        const int mb = m0 + wr * 32 + mf * 16 + lg * 4;
        #pragma unroll
        for (int nf = 0; nf < 4; ++nf) {
            const int n = n0 + wc * 64 + nf * 16 + lm;
            const float bs = bias[n];
            #pragma unroll
            for (int i = 0; i < 4; ++i)
                Out[(mb + i) * 1024 + n] = acc[mf][nf][i] + bs;
        }
    }
}
#undef STAGE
#undef GEMM_CORE

// ---------------------------------------------------------------------------
// Flash attention v12 (unchanged from r15): v8 core + XCD-chunked remap
// (FETCH 70->12 MB measured; dur-neutral but free). 8 waves x 16 q-rows,
// KVBLK=128/barrier, V tile as two [64][64] halves, XOR chunk swizzle,
// double-buffer + T14, 1 barrier/tile, swapped QK^T/PV, exp2 softmax,
// defer-max, tree reductions. LDS 80KB.
// ---------------------------------------------------------------------------
__global__ __launch_bounds__(512, 4) void attn_k(
    const short* __restrict__ Q, const short* __restrict__ K,
    const short* __restrict__ V, short* __restrict__ Ctx)
{
    __shared__ short Kl[2][128][64];
    __shared__ short Vl[2][2][64][64];   // [buf][key-half][d-row][key-chunk]
    __shared__ short Pl[8][16][64];
    const int t = threadIdx.x;
    const int flat = blockIdx.y * 16 + blockIdx.x;
    const int remap = (flat & 7) * 64 + (flat >> 3);   // 512 % 8 == 0: bijective
    const int qt = remap & 15, bh = remap >> 4;        // XCD c -> bh in [4c,4c+4)
    const int lane = t & 63, w = t >> 6;   // 8 waves
    const int lm = lane & 15, lg = lane >> 4;
    const int swz = (lm & 7) << 3;          // P-buffer swizzle (shorts)
    const int swc = lm & 7;                 // K/V read chunk swizzle

    const int qrow = qt * 128 + w * 16 + lm;
    short8 qf[2];
    #pragma unroll
    for (int ks = 0; ks < 2; ++ks)
        qf[ks] = *(const short8*)(Q + ((size_t)bh * 2048 + qrow) * 64 + ks * 32 + lg * 8);

    float m_run = -3e38f, l_run = 0.f;
    f32x4 o_acc[4] = {};

    const int rk = t >> 2, ck = t & 3;
    const int rv = t >> 3, cv = t & 7;
    const short* Kg = K + ((size_t)bh * 2048 + rk) * 64 + ck * 16;
    const short* Vg = V + ((size_t)bh * 64 + rv) * 2048 + cv * 16;
    const int koff0 = rk * 64 + ((ck * 2) ^ (rk & 7)) * 8;
    const int koff1 = rk * 64 + ((ck * 2 + 1) ^ (rk & 7)) * 8;
    const int vhalf = (cv >> 2) * 4096;
    const int voff0 = vhalf + rv * 64 + (((cv * 2) & 7) ^ (rv & 7)) * 8;
    const int voff1 = vhalf + rv * 64 + (((cv * 2 + 1) & 7) ^ (rv & 7)) * 8;

    {   // prologue: stage tile 0 into buffer 0
        short8 a = *(const short8*)(Kg);
        short8 b = *(const short8*)(Kg + 8);
        short8 c = *(const short8*)(Vg);
        short8 d = *(const short8*)(Vg + 8);
        *(short8*)((short*)Kl[0] + koff0) = a;
        *(short8*)((short*)Kl[0] + koff1) = b;
        *(short8*)((short*)Vl[0] + voff0) = c;
        *(short8*)((short*)Vl[0] + voff1) = d;
    }

    short* prow = &Pl[w][lm][0];
    int cur = 0;

    for (int kt = 0; kt < 16; ++kt) {
        __syncthreads();   // stage[cur] visible; [cur^1] free for writing

        // early-issue global loads for tile kt+1 (T14)
        short8 kn0, kn1, vn0, vn1;
        const bool pfn = (kt < 15);
        if (pfn) {
            const short* Kgn = Kg + (size_t)(kt + 1) * 8192;   // 128 rows * 64
            const short* Vgn = Vg + (kt + 1) * 128;
            kn0 = *(const short8*)(Kgn);
            kn1 = *(const short8*)(Kgn + 8);
            vn0 = *(const short8*)(Vgn);
            vn1 = *(const short8*)(Vgn + 8);
        }

        const short* Kc = (const short*)Kl[cur];
        const short* Vc = (const short*)Vl[cur];

        // ---- S^T = K Q^T, BOTH halves: lane holds q=lm, 32 key-vals ----
        f32x4 sa[2][4] = {};
        #pragma unroll
        for (int h = 0; h < 2; ++h)
            #pragma unroll
            for (int nf = 0; nf < 4; ++nf) {
                const int rr = h * 64 + nf * 16 + lm;
                #pragma unroll
                for (int ks = 0; ks < 2; ++ks) {
                    const short8 kf = *(const short8*)(Kc + rr * 64 + ((ks * 4 + lg) ^ swc) * 8);
                    sa[h][nf] = __builtin_amdgcn_mfma_f32_16x16x32_bf16(kf, qf[ks], sa[h][nf], 0, 0, 0);
                }
            }

        // ---- max reduce: pairwise tree (fmaxf nests fuse to v_max3) ----
        float mx[8];
        #pragma unroll
        for (int h = 0; h < 2; ++h)
            #pragma unroll
            for (int nf = 0; nf < 4; ++nf) {
                const f32x4 v = sa[h][nf];
                mx[h * 4 + nf] = fmaxf(fmaxf(v[0], v[1]), fmaxf(v[2], v[3]));
            }
        float mt = fmaxf(fmaxf(fmaxf(mx[0], mx[1]), fmaxf(mx[2], mx[3])),
                         fmaxf(fmaxf(mx[4], mx[5]), fmaxf(mx[6], mx[7])));
        mt = fmaxf(mt, __shfl_xor(mt, 16));
        mt = fmaxf(mt, __shfl_xor(mt, 32));
        if (__any(mt > m_run + 8.0f)) {     // defer-max (T13)
            const float mn = fmaxf(m_run, mt);
            const float alpha = exp2f(m_run - mn);
            l_run *= alpha;
            #pragma unroll
            for (int nf = 0; nf < 4; ++nf)
                #pragma unroll
                for (int i = 0; i < 4; ++i)
                    o_acc[nf][i] *= alpha;
            m_run = mn;
        }
        // exp2 + tree-structured sum (8 frag-partials -> 3-level tree)
        float ps[8];
        #pragma unroll
        for (int h = 0; h < 2; ++h)
            #pragma unroll
            for (int nf = 0; nf < 4; ++nf) {
                f32x4 v = sa[h][nf];
                #pragma unroll
                for (int i = 0; i < 4; ++i) v[i] = exp2f(v[i] - m_run);
                sa[h][nf] = v;
                ps[h * 4 + nf] = (v[0] + v[1]) + (v[2] + v[3]);
            }
        float rs = ((ps[0] + ps[1]) + (ps[2] + ps[3])) +
                   ((ps[4] + ps[5]) + (ps[6] + ps[7]));
        rs += __shfl_xor(rs, 16);
        rs += __shfl_xor(rs, 32);
        l_run += rs;

        // ---- per key-half: P-pack -> pf -> PV (P buffer reused) ----
        #pragma unroll
        for (int h = 0; h < 2; ++h) {
            #pragma unroll
            for (int nf = 0; nf < 4; ++nf) {
                uint2 pv;
                pv.x = pk_bf16(sa[h][nf][0], sa[h][nf][1]);
                pv.y = pk_bf16(sa[h][nf][2], sa[h][nf][3]);
                *(uint2*)(prow + ((nf * 16 + lg * 4) ^ swz)) = pv;
            }
            short8 pf[2];
            #pragma unroll
            for (int ks = 0; ks < 2; ++ks)
                pf[ks] = *(const short8*)(prow + ((ks * 32 + lg * 8) ^ swz));

            // late ds_write of tile kt+1 (between the two PV halves)
            if (h == 0 && pfn) {
                short* Kn = (short*)Kl[cur ^ 1];
                short* Vn = (short*)Vl[cur ^ 1];
                *(short8*)(Kn + koff0) = kn0;
                *(short8*)(Kn + koff1) = kn1;
                *(short8*)(Vn + voff0) = vn0;
                *(short8*)(Vn + voff1) = vn1;
            }

            // ctx^T += V^T P^T : lane holds q=lm, d = nf*16+lg*4+i
            #pragma unroll
            for (int nf = 0; nf < 4; ++nf) {
                const int rr = nf * 16 + lm;
                #pragma unroll
                for (int ks = 0; ks < 2; ++ks) {
                    const short8 vf = *(const short8*)(Vc + h * 4096 + rr * 64 + ((ks * 4 + lg) ^ swc) * 8);
                    o_acc[nf] = __builtin_amdgcn_mfma_f32_16x16x32_bf16(vf, pf[ks], o_acc[nf], 0, 0, 0);
                }
            }
        }
        cur ^= 1;
    }

    // epilogue: ctx[b][q][h*64 + d] bf16, 8B vector writes
    const float inv = 1.f / l_run;
    const int b = bh >> 4, h = bh & 15;
    short* outp = Ctx + ((size_t)b * 2048 + qrow) * 1024 + h * 64 + lg * 4;
    #pragma unroll
    for (int nf = 0; nf < 4; ++nf) {
        uint2 pk;
        pk.x = pk_bf16(o_acc[nf][0] * inv, o_acc[nf][1] * inv);
        pk.y = pk_bf16(o_acc[nf][2] * inv, o_acc[nf][3] * inv);
        *(uint2*)(outp + nf * 16) = pk;
    }
}

// ---------------------------------------------------------------------------
extern "C" void kernel_launch(void* const* d_in, const int* in_sizes, int n_in,
                              void* d_out, int out_size, void* d_ws, size_t ws_size,
                              hipStream_t stream)
{
    const float* query  = (const float*)d_in[0];
    const float* key_in = (const float*)d_in[1];
    const float* value  = (const float*)d_in[2];
    const float* Wq = (const float*)d_in[3];
    const float* bq = (const float*)d_in[4];
    const float* Wk = (const float*)d_in[5];
    const float* bk = (const float*)d_in[6];
    const float* Wv = (const float*)d_in[7];
    const float* bv = (const float*)d_in[8];
    const float* Wo = (const float*)d_in[9];
    const float* bo = (const float*)d_in[10];
    float* out = (float*)d_out;

    char* ws = (char*)d_ws;
    short* Wt  = (short*)(ws);               // 4 x 2MB transposed bf16 weights
    short* Abf = (short*)(ws + (8  << 20));  // 3 x 8MB bf16 inputs (q,k,v)
    short* Qh  = (short*)(ws + (32 << 20));  // [B,H,S,64] 8MB (scaled 0.125*log2e)
    short* Kh  = (short*)(ws + (40 << 20));  // [B,H,S,64] 8MB
    short* Vt  = (short*)(ws + (48 << 20));  // [B,H,64,S] 8MB
    short* Ctx = Abf;                        // Abf dead after QKV gemm; alias

    const float qscale = 0.125f * 1.44269504088896f;  // 1/sqrt(64) * log2(e)

    hipLaunchKernelGGL(prep, dim3(10240), dim3(256), 0, stream,
                       query, key_in, value, Abf, Wq, Wk, Wv, Wo, Wt);
    hipLaunchKernelGGL(gemmqkv, dim3(8, 32, 3), dim3(256), 0, stream,
                       Abf, Wt, bq, bk, bv, Qh, Kh, Vt, qscale);
    hipLaunchKernelGGL(attn_k, dim3(16, 32), dim3(512), 0, stream,
                       Qh, Kh, Vt, Ctx);
    hipLaunchKernelGGL(gemmo, dim3(8, 64), dim3(256), 0, stream,
                       Ctx, Wt + (3 << 20), bo, out);
}